// Round 1
// baseline (103.858 us; speedup 1.0000x reference)
//
#include <hip/hip_runtime.h>
#include <math.h>

// QuadConvLayer: out[b,o,m] = sum_{c,k} kern[o,c,m,k] * f[b,c,k]
// kern[o,c,m,k] = MLP_{o,c}(x(m,k)) * bump(x) * w2d(k), bump has compact
// support ||x|| < 1/6 -> only ~1-3% of (m,k) pairs are active.
// One block per m (144 blocks), 256 threads = one (o,c) MLP per thread,
// MLP weights in registers (88 floats/thread).

#define NQ 24
#define M_TOT 144
#define NB 32

__device__ __forceinline__ float sin_poly(float x) {
    // valid for |x| <= ~0.8 (we only eval inside bump support: |arg| <= 0.67)
    // fdlibm kernel-sin coefficients, truncation error < 1e-9 here
    float z = x * x;
    float r = fmaf(z, 2.7557313707070068e-06f, -1.9841269659586510e-04f);
    r = fmaf(z, r, 8.3333333332248946e-03f);
    r = fmaf(z, r, -1.6666666666666632e-01f);
    return fmaf(x * z, r, x);
}

__global__ __launch_bounds__(256)
void quadconv_kernel(const float* __restrict__ F,    // (32,16,576)
                     const float* __restrict__ OL,   // (144,2)
                     const float* __restrict__ QN,   // (24,)
                     const float* __restrict__ QW,   // (24,)
                     const float* __restrict__ W1,   // (16,16,2,8)
                     const float* __restrict__ W2,   // (16,16,8,8)
                     const float* __restrict__ W3,   // (16,16,8,1)
                     float* __restrict__ OUT) {      // (32,16,144)
    const int m = blockIdx.x;
    const int t = threadIdx.x;
    const int o = t >> 4;
    const int c = t & 15;

    __shared__ float qn_s[NQ], qw_s[NQ];
    __shared__ float f_s[512];   // f[b][c] for current k

    if (t < NQ) { qn_s[t] = QN[t]; qw_s[t] = QW[t]; }

    // Per-thread MLP weights: thread t handles pair (o,c) = (t>>4, t&15).
    // Flat layouts: W1[t*16 + d*8 + h], W2[t*64 + h*8 + g], W3[t*8 + g]
    float w1r[16], w2r[64], w3r[8];
    {
        const float4* p1 = (const float4*)(W1 + t * 16);
        #pragma unroll
        for (int i = 0; i < 4; ++i) ((float4*)w1r)[i] = p1[i];
        const float4* p2 = (const float4*)(W2 + t * 64);
        #pragma unroll
        for (int i = 0; i < 16; ++i) ((float4*)w2r)[i] = p2[i];
        const float4* p3 = (const float4*)(W3 + t * 8);
        #pragma unroll
        for (int i = 0; i < 2; ++i) ((float4*)w3r)[i] = p3[i];
    }

    const float ox = OL[2 * m];
    const float oy = OL[2 * m + 1];

    float acc[NB];
    #pragma unroll
    for (int b = 0; b < NB; ++b) acc[b] = 0.0f;

    __syncthreads();

    const float R2MAX = 1.0f / 36.0f;   // support: 1296*r2^2 < 1 -> r2 < 1/36
    for (int ik = 0; ik < NQ; ++ik) {
        float x1 = oy - qn_s[ik];
        float x1sq = x1 * x1;
        if (x1sq >= R2MAX) continue;            // block-uniform skip of 24 k's
        for (int jk = 0; jk < NQ; ++jk) {
            float x0 = ox - qn_s[jk];
            float r2 = fmaf(x0, x0, x1sq);
            float da = 1296.0f * r2 * r2;
            if (da >= 1.0f) continue;           // block-uniform: bump == 0
            float bump = 2.718281828459045f * expf(-1.0f / (1.0f - da));
            float kscale = bump * qw_s[ik] * qw_s[jk];
            int k = ik * NQ + jk;

            // stage f[:, :, k] -> f_s[b*16 + c]
            __syncthreads();   // protect previous iteration's reads
            f_s[t]       = F[o * 9216 + c * 576 + k];           // b = t>>4
            f_s[t + 256] = F[(o + 16) * 9216 + c * 576 + k];    // b = (t>>4)+16
            __syncthreads();

            // tiny MLP: 2 -> 8 -> 8 -> 1 with sin activations
            float h1[8];
            #pragma unroll
            for (int h = 0; h < 8; ++h)
                h1[h] = sin_poly(fmaf(x0, w1r[h], x1 * w1r[8 + h]));

            float wsum = 0.0f;
            #pragma unroll
            for (int g = 0; g < 8; ++g) {
                float z = h1[0] * w2r[g];
                #pragma unroll
                for (int h = 1; h < 8; ++h)
                    z = fmaf(h1[h], w2r[h * 8 + g], z);
                wsum = fmaf(sin_poly(z), w3r[g], wsum);
            }

            float kv = wsum * kscale;
            #pragma unroll
            for (int b = 0; b < NB; ++b)
                acc[b] = fmaf(kv, f_s[b * 16 + c], acc[b]);
        }
    }

    // reduce over c: lanes t = o*16 + c, xor over low 4 lane bits
    #pragma unroll
    for (int b = 0; b < NB; ++b) {
        float v = acc[b];
        v += __shfl_xor(v, 1);
        v += __shfl_xor(v, 2);
        v += __shfl_xor(v, 4);
        v += __shfl_xor(v, 8);
        acc[b] = v;
    }
    if (c == 0) {
        #pragma unroll
        for (int b = 0; b < NB; ++b)
            OUT[b * (16 * M_TOT) + o * M_TOT + m] = acc[b];
    }
}

extern "C" void kernel_launch(void* const* d_in, const int* in_sizes, int n_in,
                              void* d_out, int out_size, void* d_ws, size_t ws_size,
                              hipStream_t stream) {
    const float* F  = (const float*)d_in[0];
    const float* OL = (const float*)d_in[1];
    const float* QN = (const float*)d_in[2];
    const float* QW = (const float*)d_in[3];
    const float* W1 = (const float*)d_in[4];
    const float* W2 = (const float*)d_in[5];
    const float* W3 = (const float*)d_in[6];
    float* OUT = (float*)d_out;
    quadconv_kernel<<<dim3(M_TOT), dim3(256), 0, stream>>>(F, OL, QN, QW, W1, W2, W3, OUT);
}

// Round 2
// 95.306 us; speedup vs baseline: 1.0897x; 1.0897x over previous
//
#include <hip/hip_runtime.h>
#include <math.h>

// QuadConvLayer: out[b,o,m] = sum_{c,k} kern[o,c,m,k] * f[b,c,k]
// kern has compact support ||x(m,k)|| < 1/6 -> only ~1-3% of (m,k) active.
//
// Grid (ik=24, m=144): one block per quadrature ROW per output location.
// Rows with x1^2 >= 1/36 exit immediately (~2800 of 3456 blocks).
// Active blocks (~620): stage the whole 24-k feature row into LDS once
// (no per-k barriers), keep all 88 MLP weight floats in registers
// (__launch_bounds__(256,2) -> 256-VGPR cap so the compiler doesn't
// re-load weights inside the loop), evaluate <=6 active MLPs, and
// atomicAdd the c-reduced partials into OUT (<=5 blocks collide per m).

#define NQ 24
#define M_TOT 144
#define NB 32

__device__ __forceinline__ float sin_poly(float x) {
    // |x| <= ~0.8 inside bump support; fdlibm coeffs, err < 1e-9
    float z = x * x;
    float r = fmaf(z, 2.7557313707070068e-06f, -1.9841269659586510e-04f);
    r = fmaf(z, r, 8.3333333332248946e-03f);
    r = fmaf(z, r, -1.6666666666666632e-01f);
    return fmaf(x * z, r, x);
}

__global__ __launch_bounds__(256, 2)
void quadconv_kernel(const float* __restrict__ F,    // (32,16,576)
                     const float* __restrict__ OL,   // (144,2)
                     const float* __restrict__ QN,   // (24,)
                     const float* __restrict__ QW,   // (24,)
                     const float* __restrict__ W1,   // (16,16,2,8)
                     const float* __restrict__ W2,   // (16,16,8,8)
                     const float* __restrict__ W3,   // (16,16,8,1)
                     float* __restrict__ OUT) {      // (32,16,144)
    const int ik = blockIdx.x;
    const int m  = blockIdx.y;
    const int t  = threadIdx.x;
    const int o  = t >> 4;
    const int c  = t & 15;

    const float oy = OL[2 * m + 1];
    const float x1 = oy - QN[ik];
    const float x1sq = x1 * x1;
    if (x1sq >= 1.0f / 36.0f) return;     // block-uniform: whole row outside support

    const float ox   = OL[2 * m];
    const float qwik = QW[ik];

    __shared__ float f_s[NQ * 512];       // 48 KB: f_s[jk*512 + b*16 + c]
    __shared__ float qn_s[NQ], qw_s[NQ];

    if (t < NQ) { qn_s[t] = QN[t]; qw_s[t] = QW[t]; }

    // ---- per-thread MLP weights, kept in registers ----
    float w1r[16], w2r[64], w3r[8];
    {
        const float4* p1 = (const float4*)(W1 + t * 16);
        #pragma unroll
        for (int i = 0; i < 4; ++i) ((float4*)w1r)[i] = p1[i];
        const float4* p2 = (const float4*)(W2 + t * 64);
        #pragma unroll
        for (int i = 0; i < 16; ++i) ((float4*)w2r)[i] = p2[i];
        const float4* p3 = (const float4*)(W3 + t * 8);
        #pragma unroll
        for (int i = 0; i < 2; ++i) ((float4*)w3r)[i] = p3[i];
    }

    // ---- stage F[:, :, ik*24 .. ik*24+23] -> LDS, one shot ----
    // pair p = b*16 + c owns 24 consecutive k's (96 B, 16B-aligned)
    {
        const int kbase = ik * NQ;
        #pragma unroll
        for (int pp = 0; pp < 2; ++pp) {
            const int p  = t + pp * 256;
            const int b  = p >> 4;
            const int cc = p & 15;
            const float4* src = (const float4*)(F + b * 9216 + cc * 576 + kbase);
            float4 q[6];
            #pragma unroll
            for (int j = 0; j < 6; ++j) q[j] = src[j];
            const float* qs = (const float*)q;
            #pragma unroll
            for (int j = 0; j < NQ; ++j) f_s[j * 512 + p] = qs[j];
        }
    }
    __syncthreads();   // the only barrier

    float acc[NB];
    #pragma unroll
    for (int b = 0; b < NB; ++b) acc[b] = 0.0f;
    bool any = false;

    for (int jk = 0; jk < NQ; ++jk) {
        float x0 = ox - qn_s[jk];
        float r2 = fmaf(x0, x0, x1sq);
        float da = 1296.0f * r2 * r2;
        if (da >= 1.0f) continue;         // block-uniform
        any = true;

        float bump = 2.718281828459045f * expf(-1.0f / (1.0f - da));
        float kscale = bump * qwik * qw_s[jk];

        float h1[8];
        #pragma unroll
        for (int h = 0; h < 8; ++h)
            h1[h] = sin_poly(fmaf(x0, w1r[h], x1 * w1r[8 + h]));

        float wsum = 0.0f;
        #pragma unroll
        for (int g = 0; g < 8; ++g) {
            float z = h1[0] * w2r[g];
            #pragma unroll
            for (int h = 1; h < 8; ++h)
                z = fmaf(h1[h], w2r[h * 8 + g], z);
            wsum = fmaf(sin_poly(z), w3r[g], wsum);
        }

        float kv = wsum * kscale;
        const float* fp = &f_s[jk * 512 + c];
        #pragma unroll
        for (int b = 0; b < NB; ++b)
            acc[b] = fmaf(kv, fp[b * 16], acc[b]);
    }

    if (!any) return;                     // uniform

    // reduce over c (low 4 lane bits), then c==0 lanes accumulate to OUT
    #pragma unroll
    for (int b = 0; b < NB; ++b) {
        float v = acc[b];
        v += __shfl_xor(v, 1);
        v += __shfl_xor(v, 2);
        v += __shfl_xor(v, 4);
        v += __shfl_xor(v, 8);
        acc[b] = v;
    }
    if (c == 0) {
        #pragma unroll
        for (int b = 0; b < NB; ++b)
            atomicAdd(&OUT[b * (16 * M_TOT) + o * M_TOT + m], acc[b]);
    }
}

extern "C" void kernel_launch(void* const* d_in, const int* in_sizes, int n_in,
                              void* d_out, int out_size, void* d_ws, size_t ws_size,
                              hipStream_t stream) {
    const float* F  = (const float*)d_in[0];
    const float* OL = (const float*)d_in[1];
    const float* QN = (const float*)d_in[2];
    const float* QW = (const float*)d_in[3];
    const float* W1 = (const float*)d_in[4];
    const float* W2 = (const float*)d_in[5];
    const float* W3 = (const float*)d_in[6];
    float* OUT = (float*)d_out;
    hipMemsetAsync(d_out, 0, (size_t)out_size * sizeof(float), stream);
    quadconv_kernel<<<dim3(NQ, M_TOT), dim3(256), 0, stream>>>(F, OL, QN, QW, W1, W2, W3, OUT);
}